// Round 10
// baseline (478.073 us; speedup 1.0000x reference)
//
#include <hip/hip_runtime.h>

#define SN 6400      // H*W
#define CN 256       // channels (= GEMM K)
#define NBATCH 2
#define NTILES 50    // 128-row tiles (SN/128)
#define NCHUNK 5     // col chunks per pass (grid = 50*5*2 = 500 blocks)
#define TPC 10       // 128-col tiles per chunk
#define C10 14.4269504089f   // 10 * log2(e)

typedef _Float16 f16;
typedef f16 f16x8 __attribute__((ext_vector_type(8)));
typedef f16 f16x4 __attribute__((ext_vector_type(4)));
typedef float f32x16 __attribute__((ext_vector_type(16)));

__device__ __forceinline__ void gld16(const f16* g, f16* l) {
    __builtin_amdgcn_global_load_lds(
        (__attribute__((address_space(1))) void*)(g),
        (__attribute__((address_space(3))) void*)(l), 16, 0, 0);
}

// Stage a 128-row x 64-half (16 KB) K-chunk into LDS (256 threads).
// LDS row = 64 halfs = 8 x 16B chunks; chunk at LDS pos c holds global chunk
// c ^ (row&7). Verified conflict-free (R2/R3/R5: SQ_LDS_BANK_CONFLICT = 0).
__device__ __forceinline__ void stage64(const f16* __restrict__ gbase,
                                        f16* lbase, int tid) {
    #pragma unroll
    for (int it = 0; it < 4; ++it) {
        int q = it * 256 + tid;
        int row = q >> 3, c = q & 7;
        int cg = c ^ (row & 7);
        gld16(gbase + (size_t)row * CN + cg * 8,
              lbase + (size_t)(q & ~63) * 8);
    }
}

// ---------------- prep kernels (R5-proven) ----------------

__global__ __launch_bounds__(256) void k_meanT(const float* __restrict__ T,
                                               float* __restrict__ meanT) {
    int c = blockIdx.x, t = threadIdx.x;
    const float* p0 = T + (size_t)c * SN;
    const float* p1 = T + (size_t)(CN + c) * SN;
    float s = 0.f;
    for (int i = t; i < SN; i += 256) s += p0[i] + p1[i];
    #pragma unroll
    for (int d = 1; d < 64; d <<= 1) s += __shfl_xor(s, d, 64);
    __shared__ float sb[4];
    if ((t & 63) == 0) sb[t >> 6] = s;
    __syncthreads();
    if (t == 0) meanT[c] = (sb[0] + sb[1] + sb[2] + sb[3]) * (1.0f / 12800.0f);
}

__global__ __launch_bounds__(256) void k_xpose(const float* __restrict__ X,
                                               const float* __restrict__ meanT,
                                               f16* __restrict__ out) {
    int n = blockIdx.z, c0 = blockIdx.y * 32, s0 = blockIdx.x * 64;
    __shared__ float tile[32][65];
    int tx = threadIdx.x & 63, ty = threadIdx.x >> 6;
    const float* Xb = X + ((size_t)n * CN + c0) * SN + s0;
    #pragma unroll
    for (int cy = ty; cy < 32; cy += 4)
        tile[cy][tx] = Xb[(size_t)cy * SN + tx] - meanT[c0 + cy];
    __syncthreads();
    int cc = threadIdx.x & 31, sy = threadIdx.x >> 5;
    f16* ob = out + ((size_t)n * SN + s0) * CN + c0;
    #pragma unroll
    for (int sr = sy; sr < 64; sr += 8)
        ob[(size_t)sr * CN + cc] = (f16)tile[cc][sr];
}

__global__ __launch_bounds__(256) void k_nrm(f16* __restrict__ Ah,
                                             f16* __restrict__ Bh) {
    int w = threadIdx.x >> 6, lane = threadIdx.x & 63;
    int idx = blockIdx.x * 4 + w;
    f16x4* pa = (f16x4*)(Ah + (size_t)idx * CN + lane * 4);
    f16x4* pb = (f16x4*)(Bh + (size_t)idx * CN + lane * 4);
    f16x4 a = *pa, b = *pb;
    float sa = 0.f, sb = 0.f;
    #pragma unroll
    for (int j = 0; j < 4; ++j) {
        float x = (float)a[j]; sa += x * x;
        float y = (float)b[j]; sb += y * y;
    }
    #pragma unroll
    for (int d = 1; d < 64; d <<= 1) {
        sa += __shfl_xor(sa, d, 64);
        sb += __shfl_xor(sb, d, 64);
    }
    float ra = rsqrtf(sa), rb = rsqrtf(sb);
    #pragma unroll
    for (int j = 0; j < 4; ++j) {
        a[j] = (f16)((float)a[j] * ra);
        b[j] = (f16)((float)b[j] * rb);
    }
    *pa = a; *pb = b;
}

// ---------------- barrier-free-K-loop GEMM passes ----------------
// 256 threads, 4 waves (2x2), block tile 128x128, wave tile 64x64 as
// 2x2 MFMA tiles of 32x32x16 f16 (half the MFMA instr count of 16x16x32).
// A persistent in LDS (64 KB, one prologue barrier). B fragments stream
// DIRECTLY global->VGPR, double-buffered one K=64 stage ahead — ZERO
// __syncthreads in the K-loop, so barrier drains vanish; per-wave vmcnt
// waits overlap across the 8 resident waves.
// 32x32x16 layouts: A row=lane&31, k=(lane>>5)*8+b; B col=lane&31, same k;
// C/D col=lane&31, row=(reg&3)+8*(reg>>2)+4*(lane>>5)  [m74/m101 verified].
// PASS 0: per-row max of cos                          (fixed = I rows i)
// PASS 1: per-row sum of exp2(min(C10, a1*(cos-1)+C10)) (fixed = I rows i)
// PASS 2: per-row max over cols of (alpha_c - g_c*raw)(fixed = T rows j)
template <int PASS>
__global__ __launch_bounds__(256, 2) void k_gemm(const f16* __restrict__ A,
                                                 const f16* __restrict__ B,
                                                 const float* __restrict__ grow,
                                                 const float* __restrict__ alpha,
                                                 float* __restrict__ outP) {
    const int n = blockIdx.z, chunk = blockIdx.y, ft = blockIdx.x;
    const int tid = threadIdx.x, lane = tid & 63, wv = tid >> 6;
    const int wr = wv >> 1, wc = wv & 1;
    const int l31 = lane & 31, lh = lane >> 5;

    __shared__ f16 Ab[4][128 * 64];   // 64 KB persistent A (h-major)
    __shared__ float red[2][128];

    const f16* At = A + ((size_t)n * SN + (size_t)ft * 128) * CN;
    const f16* Bn = B + (size_t)n * SN * CN;
    const int colbase0 = chunk * (TPC * 128) + wc * 64;

    // per-lane B base pointers (col-major rows of 512 B; k offset lh*8 folded)
    const f16* Bcol[2];
    #pragma unroll
    for (int ct = 0; ct < 2; ++ct)
        Bcol[ct] = Bn + (size_t)(colbase0 + ct * 32 + l31) * CN + lh * 8;

    // ---- prefetch first B stage (t=0,h=0) before anything else ----
    f16x8 bf[2][2][4];   // [parity][ct][ks]
    #pragma unroll
    for (int ct = 0; ct < 2; ++ct)
        #pragma unroll
        for (int ks = 0; ks < 4; ++ks)
            bf[0][ct][ks] = *(const f16x8*)(Bcol[ct] + ks * 16);

    // ---- prologue: stage full A tile (DMA), single barrier ----
    #pragma unroll
    for (int h = 0; h < 4; ++h) stage64(At + h * 64, Ab[h], tid);

    // A-fragment LDS offsets (halfs): row = wr*64+rt*32+l31, chunk c=ks*2+lh
    int offA[2][4];
    #pragma unroll
    for (int rt = 0; rt < 2; ++rt) {
        int row = wr * 64 + rt * 32 + l31;
        #pragma unroll
        for (int ks = 0; ks < 4; ++ks)
            offA[rt][ks] = row * 64 + (((ks * 2 + lh) ^ (row & 7)) * 8);
    }

    // PASS1 per-row coefficients a1 = 0.5*g*log2e (a0 folded: arg=a1*(cos-1)+C10)
    float a1c[2][16];
    if constexpr (PASS == 1) {
        #pragma unroll
        for (int rt = 0; rt < 2; ++rt)
            #pragma unroll
            for (int rg = 0; rg < 16; ++rg) {
                int r = ft * 128 + wr * 64 + rt * 32 + (rg & 3) + 8 * (rg >> 2) + 4 * lh;
                a1c[rt][rg] = 0.5f * 1.44269504089f * grow[(size_t)n * SN + r];
            }
    }

    float runRow[2][16];
    #pragma unroll
    for (int rt = 0; rt < 2; ++rt)
        #pragma unroll
        for (int rg = 0; rg < 16; ++rg) runRow[rt][rg] = (PASS == 1) ? 0.f : -3.0e38f;

    __syncthreads();    // A tile landed — the ONLY barrier before the epilogue

    float gl[2], al[2];
    f32x16 acc[2][2];

    #pragma unroll 1
    for (int t = 0; t < TPC; ++t) {
        const size_t toff = (size_t)t * 128 * CN;

        if constexpr (PASS == 2) {
            #pragma unroll
            for (int ct = 0; ct < 2; ++ct) {
                int j = colbase0 + t * 128 + ct * 32 + l31;
                gl[ct] = grow[(size_t)n * SN + j];
                al[ct] = alpha[(size_t)n * SN + j];
            }
        }
        #pragma unroll
        for (int rt = 0; rt < 2; ++rt)
            #pragma unroll
            for (int ct = 0; ct < 2; ++ct) acc[rt][ct] = (f32x16)(0.f);

        #pragma unroll      // h fully unrolled: all bf/af indices constant
        for (int h = 0; h < 4; ++h) {
            const int p = h & 1;
            // prefetch next stage (t,h+1) or (t+1,0) into bf[p^1]
            if (h < 3) {
                #pragma unroll
                for (int ct = 0; ct < 2; ++ct)
                    #pragma unroll
                    for (int ks = 0; ks < 4; ++ks)
                        bf[p ^ 1][ct][ks] = *(const f16x8*)(Bcol[ct] + toff + (h + 1) * 64 + ks * 16);
            } else if (t + 1 < TPC) {
                #pragma unroll
                for (int ct = 0; ct < 2; ++ct)
                    #pragma unroll
                    for (int ks = 0; ks < 4; ++ks)
                        bf[p ^ 1][ct][ks] = *(const f16x8*)(Bcol[ct] + toff + 128 * CN + ks * 16);
            }
            // compute current stage from bf[p] + A LDS
            #pragma unroll
            for (int ks = 0; ks < 4; ++ks) {
                f16x8 af0 = *(const f16x8*)&Ab[h][offA[0][ks]];
                f16x8 af1 = *(const f16x8*)&Ab[h][offA[1][ks]];
                acc[0][0] = __builtin_amdgcn_mfma_f32_32x32x16_f16(af0, bf[p][0][ks], acc[0][0], 0, 0, 0);
                acc[0][1] = __builtin_amdgcn_mfma_f32_32x32x16_f16(af0, bf[p][1][ks], acc[0][1], 0, 0, 0);
                acc[1][0] = __builtin_amdgcn_mfma_f32_32x32x16_f16(af1, bf[p][0][ks], acc[1][0], 0, 0, 0);
                acc[1][1] = __builtin_amdgcn_mfma_f32_32x32x16_f16(af1, bf[p][1][ks], acc[1][1], 0, 0, 0);
            }
        }

        // ---- per-tile epilogue (registers only, no barrier) ----
        if constexpr (PASS == 0) {
            #pragma unroll
            for (int rt = 0; rt < 2; ++rt)
                #pragma unroll
                for (int rg = 0; rg < 16; ++rg)
                    runRow[rt][rg] = fmaxf(runRow[rt][rg],
                                           fmaxf(acc[rt][0][rg], acc[rt][1][rg]));
        } else if constexpr (PASS == 1) {
            #pragma unroll
            for (int rt = 0; rt < 2; ++rt)
                #pragma unroll
                for (int rg = 0; rg < 16; ++rg) {
                    float s = runRow[rt][rg];
                    #pragma unroll
                    for (int ct = 0; ct < 2; ++ct) {
                        float arg = fminf(C10, fmaf(a1c[rt][rg],
                                                    acc[rt][ct][rg] - 1.0f, C10));
                        s += exp2f(arg);
                    }
                    runRow[rt][rg] = s;
                }
        } else {
            #pragma unroll
            for (int rt = 0; rt < 2; ++rt)
                #pragma unroll
                for (int rg = 0; rg < 16; ++rg) {
                    #pragma unroll
                    for (int ct = 0; ct < 2; ++ct) {
                        float raw = fmaxf(0.f, fmaf(acc[rt][ct][rg], -0.5f, 0.5f));
                        float lc = fmaf(-gl[ct], raw, al[ct]);
                        runRow[rt][rg] = fmaxf(runRow[rt][rg], lc);
                    }
                }
        }
    }

    // ---- reduction: butterfly over cols (l31), cross-wc via LDS ----
    #pragma unroll
    for (int rt = 0; rt < 2; ++rt)
        #pragma unroll
        for (int rg = 0; rg < 16; ++rg) {
            float val = runRow[rt][rg];
            #pragma unroll
            for (int d = 1; d < 32; d <<= 1) {
                float o = __shfl_xor(val, d, 64);
                val = (PASS == 1) ? (val + o) : fmaxf(val, o);
            }
            runRow[rt][rg] = val;
        }
    if (l31 == 0) {
        #pragma unroll
        for (int rt = 0; rt < 2; ++rt)
            #pragma unroll
            for (int rg = 0; rg < 16; ++rg)
                red[wc][wr * 64 + rt * 32 + (rg & 3) + 8 * (rg >> 2) + 4 * lh] =
                    runRow[rt][rg];
    }
    __syncthreads();
    if (tid < 128) {
        float a = red[0][tid], b = red[1][tid];
        outP[(size_t)(n * NCHUNK + chunk) * SN + ft * 128 + tid] =
            (PASS == 1) ? (a + b) : fmaxf(a, b);
    }
}

// ---------------- small reduce kernels ----------------

__global__ __launch_bounds__(256) void r_g(const float* __restrict__ rowmaxP,
                                           float* __restrict__ grow) {
    int idx = blockIdx.x * 256 + threadIdx.x;
    int n = idx / SN, i = idx - n * SN;
    float m = -3.0e38f;
    for (int ch = 0; ch < NCHUNK; ++ch)
        m = fmaxf(m, rowmaxP[(size_t)(n * NCHUNK + ch) * SN + i]);
    float mr = fmaxf(0.f, (1.f - m) * 0.5f);
    grow[idx] = 10.f / (mr + 1e-5f);
}

__global__ __launch_bounds__(256) void r_alpha(const float* __restrict__ rowsumP,
                                               float* __restrict__ alpha) {
    int idx = blockIdx.x * 256 + threadIdx.x;
    int n = idx / SN, i = idx - n * SN;
    float s = 0.f;
    for (int ch = 0; ch < NCHUNK; ++ch)
        s += rowsumP[(size_t)(n * NCHUNK + ch) * SN + i];
    alpha[idx] = 10.f - logf(s);
}

__global__ __launch_bounds__(256) void r_colfin(const float* __restrict__ colmaxP,
                                                float* __restrict__ bsum) {
    int idx = blockIdx.x * 256 + threadIdx.x;
    int n = idx / SN, j = idx - n * SN;
    float m = -3.0e38f;
    for (int ch = 0; ch < NCHUNK; ++ch)
        m = fmaxf(m, colmaxP[(size_t)(n * NCHUNK + ch) * SN + j]);
    float v = expf(m);
    #pragma unroll
    for (int d = 1; d < 64; d <<= 1) v += __shfl_xor(v, d, 64);
    __shared__ float sb[4];
    if ((threadIdx.x & 63) == 0) sb[threadIdx.x >> 6] = v;
    __syncthreads();
    if (threadIdx.x == 0) bsum[blockIdx.x] = sb[0] + sb[1] + sb[2] + sb[3];
}

__global__ __launch_bounds__(64) void r_loss(const float* __restrict__ bsum,
                                             float* __restrict__ out) {
    int t = threadIdx.x;
    float v = (t < 50) ? bsum[t] : 0.f;
    float v0 = (t < 25) ? v : 0.f;
    float v1 = (t >= 25 && t < 50) ? v : 0.f;
    #pragma unroll
    for (int d = 1; d < 64; d <<= 1) {
        v0 += __shfl_xor(v0, d, 64);
        v1 += __shfl_xor(v1, d, 64);
    }
    if (t == 0) {
        float cs0 = v0 * (1.0f / SN), cs1 = v1 * (1.0f / SN);
        out[0] = -0.5f * (logf(cs0) + logf(cs1));
    }
}

// ---------------- launch ----------------

extern "C" void kernel_launch(void* const* d_in, const int* in_sizes, int n_in,
                              void* d_out, int out_size, void* d_ws, size_t ws_size,
                              hipStream_t stream) {
    const float* I = (const float*)d_in[0];
    const float* T = (const float*)d_in[1];
    float* out = (float*)d_out;

    float* wsf = (float*)d_ws;
    float* meanT = wsf;                        // 256
    float* grow  = meanT + 256;                // 12800
    float* alpha = grow + 12800;               // 12800
    float* rowmaxP = alpha + 12800;            // 64000
    float* rowsumP = rowmaxP + 64000;          // 64000
    float* colmaxP = rowsumP + 64000;          // 64000
    float* bsum = colmaxP + 64000;             // 64
    f16* Ah = (f16*)(bsum + 64);               // centered I, [n,s,c] fp16
    f16* Bh = Ah + (size_t)NBATCH * SN * CN;   // centered T; total ws ~14.1 MB

    k_meanT<<<256, 256, 0, stream>>>(T, meanT);
    k_xpose<<<dim3(100, 8, 2), 256, 0, stream>>>(I, meanT, Ah);
    k_xpose<<<dim3(100, 8, 2), 256, 0, stream>>>(T, meanT, Bh);
    k_nrm<<<3200, 256, 0, stream>>>(Ah, Bh);

    dim3 gg(NTILES, NCHUNK, NBATCH);
    k_gemm<0><<<gg, 256, 0, stream>>>(Ah, Bh, nullptr, nullptr, rowmaxP);
    r_g<<<50, 256, 0, stream>>>(rowmaxP, grow);
    k_gemm<1><<<gg, 256, 0, stream>>>(Ah, Bh, grow, nullptr, rowsumP);
    r_alpha<<<50, 256, 0, stream>>>(rowsumP, alpha);
    k_gemm<2><<<gg, 256, 0, stream>>>(Bh, Ah, grow, alpha, colmaxP);
    r_colfin<<<50, 256, 0, stream>>>(colmaxP, bsum);
    r_loss<<<1, 64, 0, stream>>>(bsum, out);
}